// Round 8
// baseline (100.134 us; speedup 1.0000x reference)
//
#include <hip/hip_runtime.h>

#define ENT_GRID 16
#define ENT_DIM  64
#define EMB      1024   // ENT_GRID * ENT_DIM
#define LN_EPS   1e-5f

// ---------- grouping machinery (device-side, capture-safe) ----------

__global__ void hist_kernel(const int* __restrict__ ids, int* __restrict__ hist, int B) {
    int i = blockIdx.x * blockDim.x + threadIdx.x;
    if (i < B) atomicAdd(&hist[ids[i]], 1);
}

// Single-block scan: cursor = exclusive prefix of hist; ALSO emits compacted
// work-list of non-empty relations: work[w] = {r, start, cnt, 0}.
__global__ __launch_bounds__(1024)
void scan_kernel(const int* __restrict__ hist, int* __restrict__ cursor,
                 int4* __restrict__ work, int* __restrict__ nwork, int n) {
    const int t = threadIdx.x;
    const int ITEMS = (n + 1023) / 1024;
    int vals[8];
    int lsum = 0;
#pragma unroll
    for (int k = 0; k < 8; ++k) {
        int i = t * ITEMS + k;
        int v = (k < ITEMS && i < n) ? hist[i] : 0;
        vals[k] = v;
        lsum += v;
    }
    __shared__ int s[1024];
    s[t] = lsum;
    __syncthreads();
    for (int off = 1; off < 1024; off <<= 1) {
        int v = (t >= off) ? s[t - off] : 0;
        __syncthreads();
        s[t] += v;
        __syncthreads();
    }
    int run = s[t] - lsum;
#pragma unroll
    for (int k = 0; k < 8; ++k) {
        int i = t * ITEMS + k;
        if (k < ITEMS && i < n) {
            cursor[i] = run;
            if (vals[k] > 0) {
                int idx = atomicAdd(nwork, 1);
                work[idx] = make_int4(i, run, vals[k], 0);
            }
        }
        run += vals[k];
    }
}

__global__ void scatter_kernel(const int* __restrict__ ids, int* __restrict__ cursor,
                               int* __restrict__ perm, int B) {
    int i = blockIdx.x * blockDim.x + threadIdx.x;
    if (i < B) {
        int pos = atomicAdd(&cursor[ids[i]], 1);
        perm[pos] = i;
    }
}

__device__ __forceinline__ float dot4(float4 a, float4 b) {
    return a.x * b.x + a.y * b.y + a.z * b.z + a.w * b.w;
}

// ---------- fused kernel: one block per NON-EMPTY relation ----------
// Thread t owns contiguous outputs 4t..4t+3 (tran rows 4t..4t+3 = 64 VGPR,
// loaded once); all 4 share e-block d = t>>2 (direct global, L1 broadcast).
// Per batch row: 4 dots, wave shfl-reduce, ONE lgkm-only barrier (64 B LDS,
// double-buffered), LN, one float4 store. perm depth-2 / emb depth-1 prefetch
// keeps HBM latency off the barrier-paced path.
__global__ __launch_bounds__(256, 3)
void wproj_fused_kernel(const float* __restrict__ ent_emb,
                        const float* __restrict__ rel_tran,
                        const float* __restrict__ rel_bias,
                        const float* __restrict__ ln_w,
                        const float* __restrict__ ln_b,
                        const int4*  __restrict__ work,
                        const int*   __restrict__ nwork,
                        const int*   __restrict__ perm,
                        float* __restrict__ out) {
    const int w = blockIdx.x;
    if (w >= *nwork) return;
    const int4 wk   = work[w];
    const int r     = wk.x;
    const int start = wk.y;
    const int cnt   = wk.z;
    const int t  = threadIdx.x;
    const int wv = t >> 6;
    const int d  = t >> 2;               // shared e-block for outputs 4t..4t+3

    // burst-load this thread's 4 tran rows (256 B contiguous) + params
    const float4* __restrict__ tr4 = reinterpret_cast<const float4*>(
        rel_tran + (size_t)r * (ENT_DIM * ENT_GRID * ENT_GRID) + (size_t)t * 64);
    float4 trv[16];
#pragma unroll
    for (int m = 0; m < 16; ++m) trv[m] = tr4[m];
    const float4 bv = reinterpret_cast<const float4*>(rel_bias + (size_t)r * EMB)[t];
    const float4 lw = reinterpret_cast<const float4*>(ln_w)[t];
    const float4 lb = reinterpret_cast<const float4*>(ln_b)[t];

    __shared__ float2 wred[2][4];        // [buf][wave] partial {sum, sumsq}

    // prologue: perm depth-2, emb depth-1
    const int last = start + cnt - 1;
    int b0 = perm[start];
    int b1 = perm[min(start + 1, last)];
    {
        const float4* __restrict__ e4 =
            reinterpret_cast<const float4*>(ent_emb + (size_t)b0 * EMB + d * ENT_GRID);
        float4 e0 = e4[0], e1 = e4[1], e2 = e4[2], e3 = e4[3];

        for (int j = 0; j < cnt; ++j) {
            const int jb = j & 1;
            const int bcur = b0;

            // prefetch: perm two ahead, emb one ahead (stay in flight past barrier)
            const int b2 = perm[min(start + j + 2, last)];
            const float4* __restrict__ n4 =
                reinterpret_cast<const float4*>(ent_emb + (size_t)b1 * EMB + d * ENT_GRID);
            const float4 f0 = n4[0], f1 = n4[1], f2 = n4[2], f3 = n4[3];

            const float x0 = bv.x + dot4(trv[ 0], e0) + dot4(trv[ 1], e1)
                                  + dot4(trv[ 2], e2) + dot4(trv[ 3], e3);
            const float x1 = bv.y + dot4(trv[ 4], e0) + dot4(trv[ 5], e1)
                                  + dot4(trv[ 6], e2) + dot4(trv[ 7], e3);
            const float x2 = bv.z + dot4(trv[ 8], e0) + dot4(trv[ 9], e1)
                                  + dot4(trv[10], e2) + dot4(trv[11], e3);
            const float x3 = bv.w + dot4(trv[12], e0) + dot4(trv[13], e1)
                                  + dot4(trv[14], e2) + dot4(trv[15], e3);

            float s  = x0 + x1 + x2 + x3;
            float ss = x0 * x0 + x1 * x1 + x2 * x2 + x3 * x3;
#pragma unroll
            for (int off = 32; off > 0; off >>= 1) {
                s  += __shfl_xor(s, off, 64);
                ss += __shfl_xor(ss, off, 64);
            }
            if ((t & 63) == 0) wred[jb][wv] = make_float2(s, ss);

            // publish partials; waits LDS only — vmem prefetch + stores in flight
            asm volatile("s_waitcnt lgkmcnt(0)\n\ts_barrier" ::: "memory");

            const float2 p0 = wred[jb][0], p1 = wred[jb][1],
                         p2 = wred[jb][2], p3 = wred[jb][3];
            const float ts = p0.x + p1.x + p2.x + p3.x;
            const float tq = p0.y + p1.y + p2.y + p3.y;
            const float mu   = ts * (1.0f / (float)EMB);
            const float var  = tq * (1.0f / (float)EMB) - mu * mu;
            const float rstd = rsqrtf(var + LN_EPS);

            float4 o;
            o.x = (x0 - mu) * rstd * lw.x + lb.x;
            o.y = (x1 - mu) * rstd * lw.y + lb.y;
            o.z = (x2 - mu) * rstd * lw.z + lb.z;
            o.w = (x3 - mu) * rstd * lw.w + lb.w;
            reinterpret_cast<float4*>(out + (size_t)bcur * EMB)[t] = o;  // fire & forget

            b0 = b1; b1 = b2;
            e0 = f0; e1 = f1; e2 = f2; e3 = f3;
        }
    }
}

extern "C" void kernel_launch(void* const* d_in, const int* in_sizes, int n_in,
                              void* d_out, int out_size, void* d_ws, size_t ws_size,
                              hipStream_t stream) {
    const float* ent_emb  = (const float*)d_in[0];
    const int*   proj_ids = (const int*)  d_in[1];
    const float* rel_tran = (const float*)d_in[2];
    const float* rel_bias = (const float*)d_in[3];
    const float* ln_w     = (const float*)d_in[4];
    const float* ln_b     = (const float*)d_in[5];
    float* out = (float*)d_out;

    const int B  = in_sizes[1];                                     // 8192
    const int NR = in_sizes[2] / (ENT_DIM * ENT_GRID * ENT_GRID);   // 5000

    // ws layout: [hist NR][nwork 1][cursor NR][perm B][pad][work NR*int4]
    int* ws     = (int*)d_ws;
    int* hist   = ws;                    // [NR]
    int* nwork  = ws + NR;               // [1]
    int* cursor = ws + NR + 1;           // [NR]
    int* perm   = ws + 2 * NR + 1;       // [B]
    size_t off = (size_t)(2 * NR + 1 + B) * sizeof(int);
    off = (off + 15) & ~(size_t)15;
    int4* work = (int4*)((char*)d_ws + off);   // [NR]

    hipMemsetAsync(hist, 0, (size_t)(NR + 1) * sizeof(int), stream);  // hist + nwork
    hist_kernel<<<(B + 255) / 256, 256, 0, stream>>>(proj_ids, hist, B);
    scan_kernel<<<1, 1024, 0, stream>>>(hist, cursor, work, nwork, NR);
    scatter_kernel<<<(B + 255) / 256, 256, 0, stream>>>(proj_ids, cursor, perm, B);

    wproj_fused_kernel<<<NR, 256, 0, stream>>>(ent_emb, rel_tran, rel_bias, ln_w, ln_b,
                                               work, nwork, perm, out);
}